// Round 9
// baseline (168.971 us; speedup 1.0000x reference)
//
#include <hip/hip_runtime.h>
#include <math.h>

#define N 2
#define C 19
#define H 512
#define W 512
#define PADC 50
#define WC 412
#define S 8192
#define CP 20            // fp32 P row pitch (floats)
#define XP 64            // packed row pitch (ushorts): two 32-slot K-vectors
#define NCHUNK 32
#define CHUNKT (S / NCHUNK)      // 256 t per chunk
#define TPB (CHUNKT / 32)        // 8 tile passes per block
#define NBLK ((N * S) / 8)       // refine_loss blocks = 2048
#define EPSF 1e-6f

typedef __attribute__((ext_vector_type(8))) short short8;
typedef __attribute__((ext_vector_type(16))) float f32x16;

__device__ __forceinline__ unsigned short f2bf_rne(float x) {
    unsigned u = __float_as_uint(x);
    unsigned r = (u + 0x7FFFu + ((u >> 16) & 1u)) >> 16;
    return (unsigned short)r;
}
__device__ __forceinline__ float bf2f(unsigned short h) {
    return __uint_as_float(((unsigned)h) << 16);
}
// max of 16 accs, clamped >= 0; max3-shaped
__device__ __forceinline__ float max16c(const f32x16 a) {
    float m0 = fmaxf(fmaxf(a[0], a[1]), a[2]);
    float m1 = fmaxf(fmaxf(a[3], a[4]), a[5]);
    float m2 = fmaxf(fmaxf(a[6], a[7]), a[8]);
    float m3 = fmaxf(fmaxf(a[9], a[10]), a[11]);
    float m4 = fmaxf(fmaxf(a[12], a[13]), a[14]);
    float n0 = fmaxf(fmaxf(m0, m1), m2);
    float n1 = fmaxf(fmaxf(m3, m4), a[15]);
    return fmaxf(fmaxf(n0, n1), 0.f);
}

// P32: exact fp32 rows. XA/XB: packed split-precision K=2x32 layouts so that
// slot-wise A*B gives hi.hi(19) + hi.lo(19) + lo.hi(19) (57 products in 64 slots):
//  A row: [hi(0..18), lo(0..12) | hi(0..18), lo(13..18), 0*7]
//  B row: [hi(0..18), hi(0..12) | lo(0..18), hi(13..18), 0*7]
__global__ void gather_k(const float* __restrict__ out4d,
                         const int* __restrict__ sample,
                         float* __restrict__ P32,
                         unsigned short* __restrict__ XA,
                         unsigned short* __restrict__ XB) {
    int idx = blockIdx.x * blockDim.x + threadIdx.x;   // 0 .. N*S*32-1
    int lane = idx & 63;
    int hi   = lane >> 5;
    int l    = lane & 31;
    int ns = idx >> 5;
    int nn = ns >> 13;
    int s  = ns & (S - 1);
    int smp = sample[s];
    int row = smp / WC;
    int col = smp - row * WC;
    const float* base = out4d + ((size_t)nn * C) * H * W
                      + (size_t)(PADC + row) * W + (PADC + col);
    float v = 0.f;
    if (l < C) v = base[(size_t)l * (H * W)];
    unsigned hb = f2bf_rne(v);
    unsigned lb = f2bf_rne(v - bf2f((unsigned short)hb));

    if (l < CP) P32[(size_t)ns * CP + l] = v;          // l==19 writes 0

    int base32 = hi << 5;
    int srcA = base32 + (l < C ? l : l - C);           // channel l-19 for tail
    int srcB = base32 + (l < C ? l : l - 6);           // channel l-6  for tail
    unsigned lbA = (unsigned)__shfl((int)lb, srcA, 64);
    unsigned hbA = (unsigned)__shfl((int)hb, srcA, 64);
    unsigned lbB = (unsigned)__shfl((int)lb, srcB, 64);
    unsigned hbB = (unsigned)__shfl((int)hb, srcB, 64);

    unsigned short a0 = (unsigned short)(l < C ? hb : lbA);                   // slot I
    unsigned short a1 = (unsigned short)(l < C ? hb : (l < 25 ? lbB : 0u));   // slot II
    unsigned short b0 = (unsigned short)hbA;                                  // slot I
    unsigned short b1 = (unsigned short)(l < C ? lb : (l < 25 ? hbB : 0u));   // slot II

    unsigned short* xa = XA + (size_t)ns * XP;
    unsigned short* xb = XB + (size_t)ns * XP;
    xa[l]      = a0;
    xa[32 + l] = a1;
    xb[l]      = b0;
    xb[32 + l] = b1;
}

// per (n, 1024-s-group, t-chunk of 256): per-s best (quantized sim, earliest
// tile) as packed u32 key. 8 waves; each wave owns FOUR 32-s tiles -> 16 MFMA
// per 4 ds_read_b128. Whole chunk staged once in LDS (32 KiB, slot-XOR
// swizzled: LDS[row][slot ^ (row&7)] <- X[t0+row][slot]); no mid-loop barriers.
__global__ __launch_bounds__(512, 4) void argmax_k(const unsigned short* __restrict__ XA,
                                                   const unsigned short* __restrict__ XB,
                                                   unsigned* __restrict__ keys) {
    __shared__ unsigned short lds[CHUNKT * XP];   // 32 KiB
    int b = blockIdx.x;
    int chunk  = b & (NCHUNK - 1);
    int sgroup = (b >> 5) & 7;
    int nn     = b >> 8;
    int tid  = threadIdx.x;
    int w    = tid >> 6;              // wave 0..7
    int lane = tid & 63;
    int col  = lane & 31;
    int hi   = lane >> 5;
    int t0   = chunk * CHUNKT;
    const unsigned short* XAn = XA + (size_t)nn * S * XP;
    const unsigned short* XBn = XB + (size_t)nn * S * XP;

    // 4 B-sets per wave: s tiles sgroup*1024 + (w*4+j)*32
    int sb[4];
    short8 bf[4][4];
    #pragma unroll
    for (int j = 0; j < 4; ++j) {
        sb[j] = sgroup * 1024 + (w * 4 + j) * 32;
        const unsigned short* bp = XBn + (size_t)(sb[j] + col) * XP + hi * 8;
        bf[j][0] = *(const short8*)(bp);
        bf[j][1] = *(const short8*)(bp + 16);
        bf[j][2] = *(const short8*)(bp + 32);
        bf[j][3] = *(const short8*)(bp + 48);
    }

    // prologue-only staging (registers transient): 2048 float4, 4 per thread
    #pragma unroll
    for (int k = 0; k < 4; ++k) {
        int f = k * 512 + tid;
        int row = f >> 3, slot = f & 7;
        float4 v = *(const float4*)(XAn + (size_t)(t0 + row) * XP + slot * 8);
        *(float4*)(&lds[row * XP + ((slot ^ (row & 7)) << 3)]) = v;
    }
    __syncthreads();

    f32x16 zacc = {};
    unsigned key[4] = {0u, 0u, 0u, 0u};
    int sx = col & 7;
    #pragma unroll
    for (int ts = 0; ts < TPB; ++ts) {
        const unsigned short* rbase = lds + (ts * 32 + col) * XP;
        short8 a0 = *(const short8*)(rbase + (((hi + 0) ^ sx) << 3));
        short8 a1 = *(const short8*)(rbase + (((hi + 2) ^ sx) << 3));
        short8 a2 = *(const short8*)(rbase + (((hi + 4) ^ sx) << 3));
        short8 a3 = *(const short8*)(rbase + (((hi + 6) ^ sx) << 3));
        unsigned tb = (unsigned)(63 - ts);     // larger = earlier tile
        #pragma unroll
        for (int j = 0; j < 4; ++j) {
            f32x16 acc = __builtin_amdgcn_mfma_f32_32x32x16_bf16(a0, bf[j][0], zacc, 0, 0, 0);
            acc = __builtin_amdgcn_mfma_f32_32x32x16_bf16(a1, bf[j][1], acc, 0, 0, 0);
            acc = __builtin_amdgcn_mfma_f32_32x32x16_bf16(a2, bf[j][2], acc, 0, 0, 0);
            acc = __builtin_amdgcn_mfma_f32_32x32x16_bf16(a3, bf[j][3], acc, 0, 0, 0);
            unsigned v = (__float_as_uint(max16c(acc)) & ~63u) | tb;
            key[j] = key[j] > v ? key[j] : v;
        }
    }

    size_t basek = ((size_t)nn * NCHUNK + chunk) * S;
    #pragma unroll
    for (int j = 0; j < 4; ++j) {
        unsigned o = __shfl(key[j], lane ^ 32, 64);
        unsigned k = key[j] > o ? key[j] : o;
        if (lane < 32) keys[basek + sb[j] + col] = k;
    }
}

// per s: lane-parallel merge of the 32 chunk keys (value desc, chunk asc,
// tile asc), EXACT fp32 rescan of the winning 32-row tile (first-max), then
// the 19 loss terms; fixed-order reductions -> one partial per block.
__global__ __launch_bounds__(256) void refine_loss_k(const float* __restrict__ P32,
                                                     const unsigned* __restrict__ keys,
                                                     float* __restrict__ bsum) {
    __shared__ float red[8];
    int tid = threadIdx.x;
    int lane = tid & 63;
    int hi = lane >> 5;
    int l  = lane & 31;
    int ns = blockIdx.x * 8 + (tid >> 6) * 2 + hi;   // 0 .. N*S-1
    int nn = ns >> 13;
    int s  = ns & (S - 1);

    // lane l owns chunk l; pack (val26, 31-chunk, tb) -> u64 max
    unsigned k = keys[((size_t)nn * NCHUNK + l) * S + s];
    unsigned long long key64 = ((unsigned long long)(k >> 6) << 32)
                             | (unsigned)(((31 - l) << 6) | (k & 63u));
    #pragma unroll
    for (int off = 16; off > 0; off >>= 1) {
        unsigned long long o = __shfl_xor(key64, off, 32);
        key64 = o > key64 ? o : key64;
    }
    int bc    = 31 - (int)((key64 >> 6) & 31);
    int tile  = 63 - (int)(key64 & 63);
    int tbase = bc * CHUNKT + tile * 32;

    const float* Pn = P32 + (size_t)nn * S * CP;
    const float* sr = Pn + (size_t)s * CP;
    const float* tr = Pn + (size_t)(tbase + l) * CP;
    float v = 0.f;
    #pragma unroll
    for (int c = 0; c < C; ++c) v = fmaf(sr[c], tr[c], v);
    int t = tbase + l;
    #pragma unroll
    for (int off = 16; off > 0; off >>= 1) {
        float ov = __shfl_xor(v, off, 32);
        int   ot = __shfl_xor(t, off, 32);
        if (ov > v || (ov == v && ot < t)) { v = ov; t = ot; }  // first-max
    }
    // all 32 lanes hold t*; lanes 0..18 each compute one loss term
    const float* nrow = Pn + (size_t)t * CP;
    float term = 0.f;
    if (l < C) term = -nrow[l] * logf(sr[l] + EPSF);
    #pragma unroll
    for (int off = 16; off > 0; off >>= 1)
        term += __shfl_xor(term, off, 32);
    if (l == 0) red[tid >> 5] = term;
    __syncthreads();
    if (tid == 0) {
        float a = 0.f;
        #pragma unroll
        for (int i = 0; i < 8; ++i) a += red[i];    // fixed order
        bsum[blockIdx.x] = a;
    }
}

// 2048 partials -> scalar; fixed-order tree
__global__ __launch_bounds__(256) void final_k(const float* __restrict__ bsum,
                                               float* __restrict__ out) {
    __shared__ float red[256];
    int tid = threadIdx.x;
    float a = 0.f;
    #pragma unroll
    for (int i = 0; i < NBLK / 256; ++i) a += bsum[i * 256 + tid];   // fixed order
    red[tid] = a;
    __syncthreads();
    for (int off = 128; off > 0; off >>= 1) {
        if (tid < off) red[tid] += red[tid + off];
        __syncthreads();
    }
    if (tid == 0) out[0] = red[0] / (float)(N * S * C);
}

extern "C" void kernel_launch(void* const* d_in, const int* in_sizes, int n_in,
                              void* d_out, int out_size, void* d_ws, size_t ws_size,
                              hipStream_t stream) {
    const float* out4d  = (const float*)d_in[0];
    const int*   sample = (const int*)d_in[1];

    float*          P32  = (float*)d_ws;                                // N*S*CP f32
    unsigned short* XA   = (unsigned short*)(P32 + (size_t)N * S * CP); // N*S*XP u16
    unsigned short* XB   = XA + (size_t)N * S * XP;                     // N*S*XP u16
    unsigned*       keys = (unsigned*)(XB + (size_t)N * S * XP);        // N*NCHUNK*S u32
    float*          bsum = (float*)(keys + (size_t)N * NCHUNK * S);     // NBLK f32
    float*          outp = (float*)d_out;

    gather_k<<<(N * S * 32) / 256, 256, 0, stream>>>(out4d, sample, P32, XA, XB);
    argmax_k<<<N * 8 * NCHUNK, 512, 0, stream>>>(XA, XB, keys);
    refine_loss_k<<<NBLK, 256, 0, stream>>>(P32, keys, bsum);
    final_k<<<1, 256, 0, stream>>>(bsum, outp);
}

// Round 10
// 37.930 us; speedup vs baseline: 4.4548x; 4.4548x over previous
//
#include <hip/hip_runtime.h>
#include <math.h>

#define N 2
#define C 19
#define H 512
#define W 512
#define PADC 50
#define WC 412
#define S 8192
#define CP 20            // fp32 P row pitch (floats)
#define XP 64            // packed row pitch (ushorts): two 32-slot K-vectors
#define NCHUNK 32
#define CHUNKT (S / NCHUNK)      // 256 t per chunk
#define TTS 128                  // t rows per LDS stage
#define NSTG (CHUNKT / TTS)      // 2
#define TPS (TTS / 32)           // tiles per stage = 4
#define LPITCH 72                // ushorts per LDS row (144 B)
#define NBLK ((N * S) / 8)       // refine_loss blocks = 2048
#define EPSF 1e-6f

typedef __attribute__((ext_vector_type(8))) short short8;
typedef __attribute__((ext_vector_type(16))) float f32x16;

__device__ __forceinline__ unsigned short f2bf_rne(float x) {
    unsigned u = __float_as_uint(x);
    unsigned r = (u + 0x7FFFu + ((u >> 16) & 1u)) >> 16;
    return (unsigned short)r;
}
__device__ __forceinline__ float bf2f(unsigned short h) {
    return __uint_as_float(((unsigned)h) << 16);
}
// max of 16 accs, clamped >= 0; max3-shaped
__device__ __forceinline__ float max16c(const f32x16 a) {
    float m0 = fmaxf(fmaxf(a[0], a[1]), a[2]);
    float m1 = fmaxf(fmaxf(a[3], a[4]), a[5]);
    float m2 = fmaxf(fmaxf(a[6], a[7]), a[8]);
    float m3 = fmaxf(fmaxf(a[9], a[10]), a[11]);
    float m4 = fmaxf(fmaxf(a[12], a[13]), a[14]);
    float n0 = fmaxf(fmaxf(m0, m1), m2);
    float n1 = fmaxf(fmaxf(m3, m4), a[15]);
    return fmaxf(fmaxf(n0, n1), 0.f);
}

// P32: exact fp32 rows. XA/XB: packed split-precision K=2x32 layouts so that
// slot-wise A*B gives hi.hi(19) + hi.lo(19) + lo.hi(19) (57 products in 64 slots):
//  A row: [hi(0..18), lo(0..12) | hi(0..18), lo(13..18), 0*7]
//  B row: [hi(0..18), hi(0..12) | lo(0..18), hi(13..18), 0*7]
__global__ void gather_k(const float* __restrict__ out4d,
                         const int* __restrict__ sample,
                         float* __restrict__ P32,
                         unsigned short* __restrict__ XA,
                         unsigned short* __restrict__ XB) {
    int idx = blockIdx.x * blockDim.x + threadIdx.x;   // 0 .. N*S*32-1
    int lane = idx & 63;
    int hi   = lane >> 5;
    int l    = lane & 31;
    int ns = idx >> 5;
    int nn = ns >> 13;
    int s  = ns & (S - 1);
    int smp = sample[s];
    int row = smp / WC;
    int col = smp - row * WC;
    const float* base = out4d + ((size_t)nn * C) * H * W
                      + (size_t)(PADC + row) * W + (PADC + col);
    float v = 0.f;
    if (l < C) v = base[(size_t)l * (H * W)];
    unsigned hb = f2bf_rne(v);
    unsigned lb = f2bf_rne(v - bf2f((unsigned short)hb));

    if (l < CP) P32[(size_t)ns * CP + l] = v;          // l==19 writes 0

    int base32 = hi << 5;
    int srcA = base32 + (l < C ? l : l - C);           // channel l-19 for tail
    int srcB = base32 + (l < C ? l : l - 6);           // channel l-6  for tail
    unsigned lbA = (unsigned)__shfl((int)lb, srcA, 64);
    unsigned hbA = (unsigned)__shfl((int)hb, srcA, 64);
    unsigned lbB = (unsigned)__shfl((int)lb, srcB, 64);
    unsigned hbB = (unsigned)__shfl((int)hb, srcB, 64);

    unsigned short a0 = (unsigned short)(l < C ? hb : lbA);                   // slot I
    unsigned short a1 = (unsigned short)(l < C ? hb : (l < 25 ? lbB : 0u));   // slot II
    unsigned short b0 = (unsigned short)hbA;                                  // slot I
    unsigned short b1 = (unsigned short)(l < C ? lb : (l < 25 ? hbB : 0u));   // slot II

    unsigned short* xa = XA + (size_t)ns * XP;
    unsigned short* xb = XB + (size_t)ns * XP;
    xa[l]      = a0;
    xa[32 + l] = a1;
    xb[l]      = b0;
    xb[32 + l] = b1;
}

// per (n, 512-s-group, t-chunk of 256): per-s best (quantized sim, earliest
// tile) as packed u32 key. 8 waves; each wave owns TWO 32-s tiles -> 8 MFMA
// per 4 ds_read_b128 (r7-proven register budget: fits the 64-VGPR grant).
// Double-buffered TTS=128 staging; grid 1024 -> 4 blocks/CU for stall hiding.
__global__ __launch_bounds__(512, 4) void argmax_k(const unsigned short* __restrict__ XA,
                                                   const unsigned short* __restrict__ XB,
                                                   unsigned* __restrict__ keys) {
    __shared__ unsigned short lds[2][TTS * LPITCH];   // 2 x 18432 B
    int b = blockIdx.x;
    int chunk  = b & (NCHUNK - 1);
    int sgroup = (b >> 5) & 15;
    int nn     = b >> 9;
    int tid  = threadIdx.x;
    int w    = tid >> 6;              // wave 0..7
    int lane = tid & 63;
    int col  = lane & 31;
    int hi   = lane >> 5;
    int s0   = sgroup * 512 + w * 32; // B-set A
    int s1   = s0 + 256;              // B-set B
    int t0   = chunk * CHUNKT;
    const unsigned short* XAn = XA + (size_t)nn * S * XP;
    const unsigned short* XBn = XB + (size_t)nn * S * XP;

    short8 bfA[4], bfB[4];
    {
        const unsigned short* ba = XBn + (size_t)(s0 + col) * XP + hi * 8;
        bfA[0] = *(const short8*)(ba);      bfA[1] = *(const short8*)(ba + 16);
        bfA[2] = *(const short8*)(ba + 32); bfA[3] = *(const short8*)(ba + 48);
        const unsigned short* bb = XBn + (size_t)(s1 + col) * XP + hi * 8;
        bfB[0] = *(const short8*)(bb);      bfB[1] = *(const short8*)(bb + 16);
        bfB[2] = *(const short8*)(bb + 32); bfB[3] = *(const short8*)(bb + 48);
    }

    f32x16 zacc = {};
    unsigned kA = 0u, kB = 0u;

    int r0 = tid >> 3, j0 = tid & 7;
    int r1 = r0 + 64;

    {   // prologue: stage 0 -> buf0 (128 rows x 128 B)
        const float4* src = (const float4*)(XAn + (size_t)t0 * XP);
        *(float4*)(&lds[0][r0 * LPITCH + j0 * 8]) = src[tid];
        *(float4*)(&lds[0][r1 * LPITCH + j0 * 8]) = src[tid + 512];
    }
    __syncthreads();

    int cur = 0;
    for (int st = 0; st < NSTG; ++st) {
        float4 na, nb;
        if (st + 1 < NSTG) {   // issue next-stage loads early
            const float4* srcn = (const float4*)(XAn + (size_t)(t0 + (st + 1) * TTS) * XP);
            na = srcn[tid]; nb = srcn[tid + 512];
        }
        const unsigned short* bs = &lds[cur][0];
        #pragma unroll
        for (int ts = 0; ts < TPS; ++ts) {
            const unsigned short* arow = bs + (ts * 32 + col) * LPITCH + hi * 8;
            short8 a0 = *(const short8*)(arow);
            short8 a1 = *(const short8*)(arow + 16);
            short8 a2 = *(const short8*)(arow + 32);
            short8 a3 = *(const short8*)(arow + 48);
            f32x16 accA = __builtin_amdgcn_mfma_f32_32x32x16_bf16(a0, bfA[0], zacc, 0, 0, 0);
            accA = __builtin_amdgcn_mfma_f32_32x32x16_bf16(a1, bfA[1], accA, 0, 0, 0);
            accA = __builtin_amdgcn_mfma_f32_32x32x16_bf16(a2, bfA[2], accA, 0, 0, 0);
            accA = __builtin_amdgcn_mfma_f32_32x32x16_bf16(a3, bfA[3], accA, 0, 0, 0);
            f32x16 accB = __builtin_amdgcn_mfma_f32_32x32x16_bf16(a0, bfB[0], zacc, 0, 0, 0);
            accB = __builtin_amdgcn_mfma_f32_32x32x16_bf16(a1, bfB[1], accB, 0, 0, 0);
            accB = __builtin_amdgcn_mfma_f32_32x32x16_bf16(a2, bfB[2], accB, 0, 0, 0);
            accB = __builtin_amdgcn_mfma_f32_32x32x16_bf16(a3, bfB[3], accB, 0, 0, 0);
            int tile = st * TPS + ts;              // [0,8)
            unsigned tb = (unsigned)(63 - tile);   // larger = earlier tile
            unsigned vA = (__float_as_uint(max16c(accA)) & ~63u) | tb;
            unsigned vB = (__float_as_uint(max16c(accB)) & ~63u) | tb;
            kA = kA > vA ? kA : vA;
            kB = kB > vB ? kB : vB;
        }
        if (st + 1 < NSTG) {   // write other buffer after compute; 1 barrier/stage
            *(float4*)(&lds[cur ^ 1][r0 * LPITCH + j0 * 8]) = na;
            *(float4*)(&lds[cur ^ 1][r1 * LPITCH + j0 * 8]) = nb;
        }
        __syncthreads();
        cur ^= 1;
    }

    unsigned oA = __shfl(kA, lane ^ 32, 64);
    unsigned oB = __shfl(kB, lane ^ 32, 64);
    kA = kA > oA ? kA : oA;
    kB = kB > oB ? kB : oB;
    if (lane < 32) {
        size_t basek = ((size_t)nn * NCHUNK + chunk) * S;
        keys[basek + s0 + col] = kA;
        keys[basek + s1 + col] = kB;
    }
}

// per s: lane-parallel merge of the 32 chunk keys (value desc, chunk asc,
// tile asc), EXACT fp32 rescan of the winning 32-row tile (first-max), then
// the 19 loss terms; fixed-order reductions -> one partial per block.
__global__ __launch_bounds__(256) void refine_loss_k(const float* __restrict__ P32,
                                                     const unsigned* __restrict__ keys,
                                                     float* __restrict__ bsum) {
    __shared__ float red[8];
    int tid = threadIdx.x;
    int lane = tid & 63;
    int hi = lane >> 5;
    int l  = lane & 31;
    int ns = blockIdx.x * 8 + (tid >> 6) * 2 + hi;   // 0 .. N*S-1
    int nn = ns >> 13;
    int s  = ns & (S - 1);

    // lane l owns chunk l; pack (val26, 31-chunk, tb) -> u64 max
    unsigned k = keys[((size_t)nn * NCHUNK + l) * S + s];
    unsigned long long key64 = ((unsigned long long)(k >> 6) << 32)
                             | (unsigned)(((31 - l) << 6) | (k & 63u));
    #pragma unroll
    for (int off = 16; off > 0; off >>= 1) {
        unsigned long long o = __shfl_xor(key64, off, 32);
        key64 = o > key64 ? o : key64;
    }
    int bc    = 31 - (int)((key64 >> 6) & 31);
    int tile  = 63 - (int)(key64 & 63);
    int tbase = bc * CHUNKT + tile * 32;

    const float* Pn = P32 + (size_t)nn * S * CP;
    const float* sr = Pn + (size_t)s * CP;
    const float* tr = Pn + (size_t)(tbase + l) * CP;
    float v = 0.f;
    #pragma unroll
    for (int c = 0; c < C; ++c) v = fmaf(sr[c], tr[c], v);
    int t = tbase + l;
    #pragma unroll
    for (int off = 16; off > 0; off >>= 1) {
        float ov = __shfl_xor(v, off, 32);
        int   ot = __shfl_xor(t, off, 32);
        if (ov > v || (ov == v && ot < t)) { v = ov; t = ot; }  // first-max
    }
    // all 32 lanes hold t*; lanes 0..18 each compute one loss term
    const float* nrow = Pn + (size_t)t * CP;
    float term = 0.f;
    if (l < C) term = -nrow[l] * logf(sr[l] + EPSF);
    #pragma unroll
    for (int off = 16; off > 0; off >>= 1)
        term += __shfl_xor(term, off, 32);
    if (l == 0) red[tid >> 5] = term;
    __syncthreads();
    if (tid == 0) {
        float a = 0.f;
        #pragma unroll
        for (int i = 0; i < 8; ++i) a += red[i];    // fixed order
        bsum[blockIdx.x] = a;
    }
}

// 2048 partials -> scalar; fixed-order tree
__global__ __launch_bounds__(256) void final_k(const float* __restrict__ bsum,
                                               float* __restrict__ out) {
    __shared__ float red[256];
    int tid = threadIdx.x;
    float a = 0.f;
    #pragma unroll
    for (int i = 0; i < NBLK / 256; ++i) a += bsum[i * 256 + tid];   // fixed order
    red[tid] = a;
    __syncthreads();
    for (int off = 128; off > 0; off >>= 1) {
        if (tid < off) red[tid] += red[tid + off];
        __syncthreads();
    }
    if (tid == 0) out[0] = red[0] / (float)(N * S * C);
}

extern "C" void kernel_launch(void* const* d_in, const int* in_sizes, int n_in,
                              void* d_out, int out_size, void* d_ws, size_t ws_size,
                              hipStream_t stream) {
    const float* out4d  = (const float*)d_in[0];
    const int*   sample = (const int*)d_in[1];

    float*          P32  = (float*)d_ws;                                // N*S*CP f32
    unsigned short* XA   = (unsigned short*)(P32 + (size_t)N * S * CP); // N*S*XP u16
    unsigned short* XB   = XA + (size_t)N * S * XP;                     // N*S*XP u16
    unsigned*       keys = (unsigned*)(XB + (size_t)N * S * XP);        // N*NCHUNK*S u32
    float*          bsum = (float*)(keys + (size_t)N * NCHUNK * S);     // NBLK f32
    float*          outp = (float*)d_out;

    gather_k<<<(N * S * 32) / 256, 256, 0, stream>>>(out4d, sample, P32, XA, XB);
    argmax_k<<<N * 16 * NCHUNK, 512, 0, stream>>>(XA, XB, keys);
    refine_loss_k<<<NBLK, 256, 0, stream>>>(P32, keys, bsum);
    final_k<<<1, 256, 0, stream>>>(bsum, outp);
}

// Round 11
// 35.955 us; speedup vs baseline: 4.6995x; 1.0549x over previous
//
#include <hip/hip_runtime.h>
#include <math.h>

#define N 2
#define C 19
#define H 512
#define W 512
#define PADC 50
#define WC 412
#define S 8192
#define CP 20            // fp32 P row pitch (floats)
#define XP 64            // packed row pitch (ushorts): two 32-slot K-vectors
#define NCHUNK 16
#define CHUNKT (S / NCHUNK)      // 512 t per chunk
#define TTS 128                  // t rows per LDS stage
#define NSTG (CHUNKT / TTS)      // 4
#define TPS (TTS / 32)           // tiles per stage = 4
#define LPITCH 72                // ushorts per LDS row (144 B)
#define NBLK ((N * S) / 8)       // refine_loss blocks = 2048
#define EPSF 1e-6f

typedef __attribute__((ext_vector_type(8))) short short8;
typedef __attribute__((ext_vector_type(16))) float f32x16;

__device__ __forceinline__ unsigned short f2bf_rne(float x) {
    unsigned u = __float_as_uint(x);
    unsigned r = (u + 0x7FFFu + ((u >> 16) & 1u)) >> 16;
    return (unsigned short)r;
}
__device__ __forceinline__ float bf2f(unsigned short h) {
    return __uint_as_float(((unsigned)h) << 16);
}
// max of 16 accs, clamped >= 0; max3-shaped
__device__ __forceinline__ float max16c(const f32x16 a) {
    float m0 = fmaxf(fmaxf(a[0], a[1]), a[2]);
    float m1 = fmaxf(fmaxf(a[3], a[4]), a[5]);
    float m2 = fmaxf(fmaxf(a[6], a[7]), a[8]);
    float m3 = fmaxf(fmaxf(a[9], a[10]), a[11]);
    float m4 = fmaxf(fmaxf(a[12], a[13]), a[14]);
    float n0 = fmaxf(fmaxf(m0, m1), m2);
    float n1 = fmaxf(fmaxf(m3, m4), a[15]);
    return fmaxf(fmaxf(n0, n1), 0.f);
}

// P32: exact fp32 rows. XA/XB: packed split-precision K=2x32 layouts so that
// slot-wise A*B gives hi.hi(19) + hi.lo(19) + lo.hi(19) (57 products in 64 slots):
//  A row: [hi(0..18), lo(0..12) | hi(0..18), lo(13..18), 0*7]
//  B row: [hi(0..18), hi(0..12) | lo(0..18), hi(13..18), 0*7]
__global__ void gather_k(const float* __restrict__ out4d,
                         const int* __restrict__ sample,
                         float* __restrict__ P32,
                         unsigned short* __restrict__ XA,
                         unsigned short* __restrict__ XB) {
    int idx = blockIdx.x * blockDim.x + threadIdx.x;   // 0 .. N*S*32-1
    int lane = idx & 63;
    int hi   = lane >> 5;
    int l    = lane & 31;
    int ns = idx >> 5;
    int nn = ns >> 13;
    int s  = ns & (S - 1);
    int smp = sample[s];
    int row = smp / WC;
    int col = smp - row * WC;
    const float* base = out4d + ((size_t)nn * C) * H * W
                      + (size_t)(PADC + row) * W + (PADC + col);
    float v = 0.f;
    if (l < C) v = base[(size_t)l * (H * W)];
    unsigned hb = f2bf_rne(v);
    unsigned lb = f2bf_rne(v - bf2f((unsigned short)hb));

    if (l < CP) P32[(size_t)ns * CP + l] = v;          // l==19 writes 0

    int base32 = hi << 5;
    int srcA = base32 + (l < C ? l : l - C);           // channel l-19 for tail
    int srcB = base32 + (l < C ? l : l - 6);           // channel l-6  for tail
    unsigned lbA = (unsigned)__shfl((int)lb, srcA, 64);
    unsigned hbA = (unsigned)__shfl((int)hb, srcA, 64);
    unsigned lbB = (unsigned)__shfl((int)lb, srcB, 64);
    unsigned hbB = (unsigned)__shfl((int)hb, srcB, 64);

    unsigned short a0 = (unsigned short)(l < C ? hb : lbA);                   // slot I
    unsigned short a1 = (unsigned short)(l < C ? hb : (l < 25 ? lbB : 0u));   // slot II
    unsigned short b0 = (unsigned short)hbA;                                  // slot I
    unsigned short b1 = (unsigned short)(l < C ? lb : (l < 25 ? hbB : 0u));   // slot II

    unsigned short* xa = XA + (size_t)ns * XP;
    unsigned short* xb = XB + (size_t)ns * XP;
    xa[l]      = a0;
    xa[32 + l] = a1;
    xb[l]      = b0;
    xb[32 + l] = b1;
}

// per (n, 256-s-group, t-chunk of 512): per-s best (quantized sim, earliest
// tile) as packed u32 key. 4 waves/block; each wave owns TWO 32-s tiles ->
// 8 MFMA per 4 ds_read_b128 (r7-proven register budget). Grid 1024 =
// 4 blocks/CU -> 4 waves/SIMD: 8 concurrent MFMA chains hide dep latency.
__global__ __launch_bounds__(256, 4) void argmax_k(const unsigned short* __restrict__ XA,
                                                   const unsigned short* __restrict__ XB,
                                                   unsigned* __restrict__ keys) {
    __shared__ unsigned short lds[2][TTS * LPITCH];   // 2 x 18432 B
    int b = blockIdx.x;
    int chunk  = b & (NCHUNK - 1);
    int sgroup = (b >> 4) & 31;
    int nn     = b >> 9;
    int tid  = threadIdx.x;
    int w    = tid >> 6;              // wave 0..3
    int lane = tid & 63;
    int col  = lane & 31;
    int hi   = lane >> 5;
    int s0   = sgroup * 256 + w * 32; // B-set A
    int s1   = s0 + 128;              // B-set B
    int t0   = chunk * CHUNKT;
    const unsigned short* XAn = XA + (size_t)nn * S * XP;
    const unsigned short* XBn = XB + (size_t)nn * S * XP;

    short8 bfA[4], bfB[4];
    {
        const unsigned short* ba = XBn + (size_t)(s0 + col) * XP + hi * 8;
        bfA[0] = *(const short8*)(ba);      bfA[1] = *(const short8*)(ba + 16);
        bfA[2] = *(const short8*)(ba + 32); bfA[3] = *(const short8*)(ba + 48);
        const unsigned short* bb = XBn + (size_t)(s1 + col) * XP + hi * 8;
        bfB[0] = *(const short8*)(bb);      bfB[1] = *(const short8*)(bb + 16);
        bfB[2] = *(const short8*)(bb + 32); bfB[3] = *(const short8*)(bb + 48);
    }

    f32x16 zacc = {};
    unsigned kA = 0u, kB = 0u;

    {   // prologue: stage 0 -> buf0 (128 rows x 128 B = 1024 float4, 4/thread)
        const float4* src = (const float4*)(XAn + (size_t)t0 * XP);
        #pragma unroll
        for (int k = 0; k < 4; ++k) {
            int f = k * 256 + tid;
            *(float4*)(&lds[0][(f >> 3) * LPITCH + (f & 7) * 8]) = src[f];
        }
    }
    __syncthreads();

    int cur = 0;
    for (int st = 0; st < NSTG; ++st) {
        float4 nx[4];
        if (st + 1 < NSTG) {   // issue next-stage loads early
            const float4* srcn = (const float4*)(XAn + (size_t)(t0 + (st + 1) * TTS) * XP);
            #pragma unroll
            for (int k = 0; k < 4; ++k) nx[k] = srcn[k * 256 + tid];
        }
        const unsigned short* bs = &lds[cur][0];
        #pragma unroll
        for (int ts = 0; ts < TPS; ++ts) {
            const unsigned short* arow = bs + (ts * 32 + col) * LPITCH + hi * 8;
            short8 a0 = *(const short8*)(arow);
            short8 a1 = *(const short8*)(arow + 16);
            short8 a2 = *(const short8*)(arow + 32);
            short8 a3 = *(const short8*)(arow + 48);
            f32x16 accA = __builtin_amdgcn_mfma_f32_32x32x16_bf16(a0, bfA[0], zacc, 0, 0, 0);
            accA = __builtin_amdgcn_mfma_f32_32x32x16_bf16(a1, bfA[1], accA, 0, 0, 0);
            accA = __builtin_amdgcn_mfma_f32_32x32x16_bf16(a2, bfA[2], accA, 0, 0, 0);
            accA = __builtin_amdgcn_mfma_f32_32x32x16_bf16(a3, bfA[3], accA, 0, 0, 0);
            f32x16 accB = __builtin_amdgcn_mfma_f32_32x32x16_bf16(a0, bfB[0], zacc, 0, 0, 0);
            accB = __builtin_amdgcn_mfma_f32_32x32x16_bf16(a1, bfB[1], accB, 0, 0, 0);
            accB = __builtin_amdgcn_mfma_f32_32x32x16_bf16(a2, bfB[2], accB, 0, 0, 0);
            accB = __builtin_amdgcn_mfma_f32_32x32x16_bf16(a3, bfB[3], accB, 0, 0, 0);
            int tile = st * TPS + ts;              // [0,16)
            unsigned tb = (unsigned)(63 - tile);   // larger = earlier tile
            unsigned vA = (__float_as_uint(max16c(accA)) & ~63u) | tb;
            unsigned vB = (__float_as_uint(max16c(accB)) & ~63u) | tb;
            kA = kA > vA ? kA : vA;
            kB = kB > vB ? kB : vB;
        }
        if (st + 1 < NSTG) {   // write other buffer after compute; 1 barrier/stage
            #pragma unroll
            for (int k = 0; k < 4; ++k) {
                int f = k * 256 + tid;
                *(float4*)(&lds[cur ^ 1][(f >> 3) * LPITCH + (f & 7) * 8]) = nx[k];
            }
        }
        __syncthreads();
        cur ^= 1;
    }

    unsigned oA = __shfl(kA, lane ^ 32, 64);
    unsigned oB = __shfl(kB, lane ^ 32, 64);
    kA = kA > oA ? kA : oA;
    kB = kB > oB ? kB : oB;
    if (lane < 32) {
        size_t basek = ((size_t)nn * NCHUNK + chunk) * S;
        keys[basek + s0 + col] = kA;
        keys[basek + s1 + col] = kB;
    }
}

// per s: lane-parallel merge of the 16 chunk keys (value desc, chunk asc,
// tile asc; lanes 16..31 mirror 0..15 -- duplicates harmless under max),
// EXACT fp32 rescan of the winning 32-row tile (first-max), then the 19
// loss terms; fixed-order reductions -> one partial per block.
__global__ __launch_bounds__(256) void refine_loss_k(const float* __restrict__ P32,
                                                     const unsigned* __restrict__ keys,
                                                     float* __restrict__ bsum) {
    __shared__ float red[8];
    int tid = threadIdx.x;
    int lane = tid & 63;
    int hi = lane >> 5;
    int l  = lane & 31;
    int ns = blockIdx.x * 8 + (tid >> 6) * 2 + hi;   // 0 .. N*S-1
    int nn = ns >> 13;
    int s  = ns & (S - 1);

    // lane l owns chunk l&15; pack (val26, 15-chunk, tb) -> u64 max
    int cl = l & (NCHUNK - 1);
    unsigned k = keys[((size_t)nn * NCHUNK + cl) * S + s];
    unsigned long long key64 = ((unsigned long long)(k >> 6) << 32)
                             | (unsigned)((((NCHUNK - 1) - cl) << 6) | (k & 63u));
    #pragma unroll
    for (int off = 16; off > 0; off >>= 1) {
        unsigned long long o = __shfl_xor(key64, off, 32);
        key64 = o > key64 ? o : key64;
    }
    int bc    = (NCHUNK - 1) - (int)((key64 >> 6) & (NCHUNK - 1));
    int tile  = 63 - (int)(key64 & 63);
    int tbase = bc * CHUNKT + tile * 32;

    const float* Pn = P32 + (size_t)nn * S * CP;
    const float* sr = Pn + (size_t)s * CP;
    const float* tr = Pn + (size_t)(tbase + l) * CP;
    float v = 0.f;
    #pragma unroll
    for (int c = 0; c < C; ++c) v = fmaf(sr[c], tr[c], v);
    int t = tbase + l;
    #pragma unroll
    for (int off = 16; off > 0; off >>= 1) {
        float ov = __shfl_xor(v, off, 32);
        int   ot = __shfl_xor(t, off, 32);
        if (ov > v || (ov == v && ot < t)) { v = ov; t = ot; }  // first-max
    }
    // all 32 lanes hold t*; lanes 0..18 each compute one loss term
    const float* nrow = Pn + (size_t)t * CP;
    float term = 0.f;
    if (l < C) term = -nrow[l] * logf(sr[l] + EPSF);
    #pragma unroll
    for (int off = 16; off > 0; off >>= 1)
        term += __shfl_xor(term, off, 32);
    if (l == 0) red[tid >> 5] = term;
    __syncthreads();
    if (tid == 0) {
        float a = 0.f;
        #pragma unroll
        for (int i = 0; i < 8; ++i) a += red[i];    // fixed order
        bsum[blockIdx.x] = a;
    }
}

// 2048 partials -> scalar; fixed-order tree
__global__ __launch_bounds__(256) void final_k(const float* __restrict__ bsum,
                                               float* __restrict__ out) {
    __shared__ float red[256];
    int tid = threadIdx.x;
    float a = 0.f;
    #pragma unroll
    for (int i = 0; i < NBLK / 256; ++i) a += bsum[i * 256 + tid];   // fixed order
    red[tid] = a;
    __syncthreads();
    for (int off = 128; off > 0; off >>= 1) {
        if (tid < off) red[tid] += red[tid + off];
        __syncthreads();
    }
    if (tid == 0) out[0] = red[0] / (float)(N * S * C);
}

extern "C" void kernel_launch(void* const* d_in, const int* in_sizes, int n_in,
                              void* d_out, int out_size, void* d_ws, size_t ws_size,
                              hipStream_t stream) {
    const float* out4d  = (const float*)d_in[0];
    const int*   sample = (const int*)d_in[1];

    float*          P32  = (float*)d_ws;                                // N*S*CP f32
    unsigned short* XA   = (unsigned short*)(P32 + (size_t)N * S * CP); // N*S*XP u16
    unsigned short* XB   = XA + (size_t)N * S * XP;                     // N*S*XP u16
    unsigned*       keys = (unsigned*)(XB + (size_t)N * S * XP);        // N*NCHUNK*S u32
    float*          bsum = (float*)(keys + (size_t)N * NCHUNK * S);     // NBLK f32
    float*          outp = (float*)d_out;

    gather_k<<<(N * S * 32) / 256, 256, 0, stream>>>(out4d, sample, P32, XA, XB);
    argmax_k<<<N * 32 * NCHUNK, 256, 0, stream>>>(XA, XB, keys);
    refine_loss_k<<<NBLK, 256, 0, stream>>>(P32, keys, bsum);
    final_k<<<1, 256, 0, stream>>>(bsum, outp);
}

// Round 12
// 35.611 us; speedup vs baseline: 4.7449x; 1.0096x over previous
//
#include <hip/hip_runtime.h>
#include <math.h>

#define N 2
#define C 19
#define H 512
#define W 512
#define PADC 50
#define WC 412
#define S 8192
#define CP 20            // fp32 P row pitch (floats)
#define XP 64            // packed row pitch (ushorts): two 32-slot K-vectors
#define NCHUNK 16
#define CHUNKT (S / NCHUNK)      // 512 t per chunk
#define TTS 128                  // t rows per LDS stage
#define NSTG (CHUNKT / TTS)      // 4
#define TPS (TTS / 32)           // tiles per stage = 4
#define LPITCH 72                // ushorts per LDS row (144 B)
#define NBLK ((N * S) / 8)       // refine_loss blocks = 2048
#define EPSF 1e-6f

typedef __attribute__((ext_vector_type(8))) short short8;
typedef __attribute__((ext_vector_type(16))) float f32x16;

__device__ __forceinline__ unsigned short f2bf_rne(float x) {
    unsigned u = __float_as_uint(x);
    unsigned r = (u + 0x7FFFu + ((u >> 16) & 1u)) >> 16;
    return (unsigned short)r;
}
__device__ __forceinline__ float bf2f(unsigned short h) {
    return __uint_as_float(((unsigned)h) << 16);
}
// HW 3-input max (VOP3); non-volatile so the scheduler can interleave
__device__ __forceinline__ float max3f(float a, float b, float c) {
    float d;
    asm("v_max3_f32 %0, %1, %2, %3" : "=v"(d) : "v"(a), "v"(b), "v"(c));
    return d;
}
__device__ __forceinline__ float max3f_c0(float a, float b) {   // max(a,b,0)
    float d;
    asm("v_max3_f32 %0, %1, %2, 0" : "=v"(d) : "v"(a), "v"(b));
    return d;
}
// max of 16 accs, clamped >= 0: 8 v_max3 total
__device__ __forceinline__ float max16c(const f32x16 a) {
    float m0 = max3f(a[0],  a[1],  a[2]);
    float m1 = max3f(a[3],  a[4],  a[5]);
    float m2 = max3f(a[6],  a[7],  a[8]);
    float m3 = max3f(a[9],  a[10], a[11]);
    float m4 = max3f(a[12], a[13], a[14]);
    float n0 = max3f(m0, m1, m2);
    float n1 = max3f(m3, m4, a[15]);
    return max3f_c0(n0, n1);
}

// P32: exact fp32 rows. XA/XB: packed split-precision K=2x32 layouts so that
// slot-wise A*B gives hi.hi(19) + hi.lo(19) + lo.hi(19) (57 products in 64 slots):
//  A row: [hi(0..18), lo(0..12) | hi(0..18), lo(13..18), 0*7]
//  B row: [hi(0..18), hi(0..12) | lo(0..18), hi(13..18), 0*7]
__global__ void gather_k(const float* __restrict__ out4d,
                         const int* __restrict__ sample,
                         float* __restrict__ P32,
                         unsigned short* __restrict__ XA,
                         unsigned short* __restrict__ XB) {
    int idx = blockIdx.x * blockDim.x + threadIdx.x;   // 0 .. N*S*32-1
    int lane = idx & 63;
    int hi   = lane >> 5;
    int l    = lane & 31;
    int ns = idx >> 5;
    int nn = ns >> 13;
    int s  = ns & (S - 1);
    int smp = sample[s];
    int row = smp / WC;
    int col = smp - row * WC;
    const float* base = out4d + ((size_t)nn * C) * H * W
                      + (size_t)(PADC + row) * W + (PADC + col);
    float v = 0.f;
    if (l < C) v = base[(size_t)l * (H * W)];
    unsigned hb = f2bf_rne(v);
    unsigned lb = f2bf_rne(v - bf2f((unsigned short)hb));

    if (l < CP) P32[(size_t)ns * CP + l] = v;          // l==19 writes 0

    int base32 = hi << 5;
    int srcA = base32 + (l < C ? l : l - C);           // channel l-19 for tail
    int srcB = base32 + (l < C ? l : l - 6);           // channel l-6  for tail
    unsigned lbA = (unsigned)__shfl((int)lb, srcA, 64);
    unsigned hbA = (unsigned)__shfl((int)hb, srcA, 64);
    unsigned lbB = (unsigned)__shfl((int)lb, srcB, 64);
    unsigned hbB = (unsigned)__shfl((int)hb, srcB, 64);

    unsigned short a0 = (unsigned short)(l < C ? hb : lbA);                   // slot I
    unsigned short a1 = (unsigned short)(l < C ? hb : (l < 25 ? lbB : 0u));   // slot II
    unsigned short b0 = (unsigned short)hbA;                                  // slot I
    unsigned short b1 = (unsigned short)(l < C ? lb : (l < 25 ? hbB : 0u));   // slot II

    unsigned short* xa = XA + (size_t)ns * XP;
    unsigned short* xb = XB + (size_t)ns * XP;
    xa[l]      = a0;
    xa[32 + l] = a1;
    xb[l]      = b0;
    xb[32 + l] = b1;
}

// per (n, 256-s-group, t-chunk of 512): per-s best (quantized sim, earliest
// tile) as packed u32 key. 4 waves/block; each wave owns TWO 32-s tiles ->
// 8 MFMA per 4 ds_read_b128. Grid 1024 = 4 blocks/CU. Scan via v_max3.
__global__ __launch_bounds__(256, 4) void argmax_k(const unsigned short* __restrict__ XA,
                                                   const unsigned short* __restrict__ XB,
                                                   unsigned* __restrict__ keys) {
    __shared__ unsigned short lds[2][TTS * LPITCH];   // 2 x 18432 B
    int b = blockIdx.x;
    int chunk  = b & (NCHUNK - 1);
    int sgroup = (b >> 4) & 31;
    int nn     = b >> 9;
    int tid  = threadIdx.x;
    int w    = tid >> 6;              // wave 0..3
    int lane = tid & 63;
    int col  = lane & 31;
    int hi   = lane >> 5;
    int s0   = sgroup * 256 + w * 32; // B-set A
    int s1   = s0 + 128;              // B-set B
    int t0   = chunk * CHUNKT;
    const unsigned short* XAn = XA + (size_t)nn * S * XP;
    const unsigned short* XBn = XB + (size_t)nn * S * XP;

    short8 bfA[4], bfB[4];
    {
        const unsigned short* ba = XBn + (size_t)(s0 + col) * XP + hi * 8;
        bfA[0] = *(const short8*)(ba);      bfA[1] = *(const short8*)(ba + 16);
        bfA[2] = *(const short8*)(ba + 32); bfA[3] = *(const short8*)(ba + 48);
        const unsigned short* bb = XBn + (size_t)(s1 + col) * XP + hi * 8;
        bfB[0] = *(const short8*)(bb);      bfB[1] = *(const short8*)(bb + 16);
        bfB[2] = *(const short8*)(bb + 32); bfB[3] = *(const short8*)(bb + 48);
    }

    f32x16 zacc = {};
    unsigned kA = 0u, kB = 0u;

    {   // prologue: stage 0 -> buf0 (128 rows x 128 B = 1024 float4, 4/thread)
        const float4* src = (const float4*)(XAn + (size_t)t0 * XP);
        #pragma unroll
        for (int k = 0; k < 4; ++k) {
            int f = k * 256 + tid;
            *(float4*)(&lds[0][(f >> 3) * LPITCH + (f & 7) * 8]) = src[f];
        }
    }
    __syncthreads();

    int cur = 0;
    for (int st = 0; st < NSTG; ++st) {
        float4 nx[4];
        if (st + 1 < NSTG) {   // issue next-stage loads early
            const float4* srcn = (const float4*)(XAn + (size_t)(t0 + (st + 1) * TTS) * XP);
            #pragma unroll
            for (int k = 0; k < 4; ++k) nx[k] = srcn[k * 256 + tid];
        }
        const unsigned short* bs = &lds[cur][0];
        #pragma unroll
        for (int ts = 0; ts < TPS; ++ts) {
            const unsigned short* arow = bs + (ts * 32 + col) * LPITCH + hi * 8;
            short8 a0 = *(const short8*)(arow);
            short8 a1 = *(const short8*)(arow + 16);
            short8 a2 = *(const short8*)(arow + 32);
            short8 a3 = *(const short8*)(arow + 48);
            f32x16 accA = __builtin_amdgcn_mfma_f32_32x32x16_bf16(a0, bfA[0], zacc, 0, 0, 0);
            accA = __builtin_amdgcn_mfma_f32_32x32x16_bf16(a1, bfA[1], accA, 0, 0, 0);
            accA = __builtin_amdgcn_mfma_f32_32x32x16_bf16(a2, bfA[2], accA, 0, 0, 0);
            accA = __builtin_amdgcn_mfma_f32_32x32x16_bf16(a3, bfA[3], accA, 0, 0, 0);
            f32x16 accB = __builtin_amdgcn_mfma_f32_32x32x16_bf16(a0, bfB[0], zacc, 0, 0, 0);
            accB = __builtin_amdgcn_mfma_f32_32x32x16_bf16(a1, bfB[1], accB, 0, 0, 0);
            accB = __builtin_amdgcn_mfma_f32_32x32x16_bf16(a2, bfB[2], accB, 0, 0, 0);
            accB = __builtin_amdgcn_mfma_f32_32x32x16_bf16(a3, bfB[3], accB, 0, 0, 0);
            int tile = st * TPS + ts;              // [0,16)
            unsigned tb = (unsigned)(63 - tile);   // larger = earlier tile
            unsigned vA = (__float_as_uint(max16c(accA)) & ~63u) | tb;
            unsigned vB = (__float_as_uint(max16c(accB)) & ~63u) | tb;
            kA = kA > vA ? kA : vA;
            kB = kB > vB ? kB : vB;
        }
        if (st + 1 < NSTG) {   // write other buffer after compute; 1 barrier/stage
            #pragma unroll
            for (int k = 0; k < 4; ++k) {
                int f = k * 256 + tid;
                *(float4*)(&lds[cur ^ 1][(f >> 3) * LPITCH + (f & 7) * 8]) = nx[k];
            }
        }
        __syncthreads();
        cur ^= 1;
    }

    unsigned oA = __shfl(kA, lane ^ 32, 64);
    unsigned oB = __shfl(kB, lane ^ 32, 64);
    kA = kA > oA ? kA : oA;
    kB = kB > oB ? kB : oB;
    if (lane < 32) {
        size_t basek = ((size_t)nn * NCHUNK + chunk) * S;
        keys[basek + s0 + col] = kA;
        keys[basek + s1 + col] = kB;
    }
}

// per s: lane-parallel merge of the 16 chunk keys (value desc, chunk asc,
// tile asc; lanes 16..31 mirror 0..15 -- duplicates harmless under max),
// EXACT fp32 rescan of the winning 32-row tile (first-max), then the 19
// loss terms; fixed-order reductions -> one partial per block.
__global__ __launch_bounds__(256) void refine_loss_k(const float* __restrict__ P32,
                                                     const unsigned* __restrict__ keys,
                                                     float* __restrict__ bsum) {
    __shared__ float red[8];
    int tid = threadIdx.x;
    int lane = tid & 63;
    int hi = lane >> 5;
    int l  = lane & 31;
    int ns = blockIdx.x * 8 + (tid >> 6) * 2 + hi;   // 0 .. N*S-1
    int nn = ns >> 13;
    int s  = ns & (S - 1);

    // lane l owns chunk l&15; pack (val26, 15-chunk, tb) -> u64 max
    int cl = l & (NCHUNK - 1);
    unsigned k = keys[((size_t)nn * NCHUNK + cl) * S + s];
    unsigned long long key64 = ((unsigned long long)(k >> 6) << 32)
                             | (unsigned)((((NCHUNK - 1) - cl) << 6) | (k & 63u));
    #pragma unroll
    for (int off = 16; off > 0; off >>= 1) {
        unsigned long long o = __shfl_xor(key64, off, 32);
        key64 = o > key64 ? o : key64;
    }
    int bc    = (NCHUNK - 1) - (int)((key64 >> 6) & (NCHUNK - 1));
    int tile  = 63 - (int)(key64 & 63);
    int tbase = bc * CHUNKT + tile * 32;

    const float* Pn = P32 + (size_t)nn * S * CP;
    const float* sr = Pn + (size_t)s * CP;
    const float* tr = Pn + (size_t)(tbase + l) * CP;
    float v = 0.f;
    #pragma unroll
    for (int c = 0; c < C; ++c) v = fmaf(sr[c], tr[c], v);
    int t = tbase + l;
    #pragma unroll
    for (int off = 16; off > 0; off >>= 1) {
        float ov = __shfl_xor(v, off, 32);
        int   ot = __shfl_xor(t, off, 32);
        if (ov > v || (ov == v && ot < t)) { v = ov; t = ot; }  // first-max
    }
    // all 32 lanes hold t*; lanes 0..18 each compute one loss term
    const float* nrow = Pn + (size_t)t * CP;
    float term = 0.f;
    if (l < C) term = -nrow[l] * logf(sr[l] + EPSF);
    #pragma unroll
    for (int off = 16; off > 0; off >>= 1)
        term += __shfl_xor(term, off, 32);
    if (l == 0) red[tid >> 5] = term;
    __syncthreads();
    if (tid == 0) {
        float a = 0.f;
        #pragma unroll
        for (int i = 0; i < 8; ++i) a += red[i];    // fixed order
        bsum[blockIdx.x] = a;
    }
}

// 2048 partials -> scalar; fixed-order tree
__global__ __launch_bounds__(256) void final_k(const float* __restrict__ bsum,
                                               float* __restrict__ out) {
    __shared__ float red[256];
    int tid = threadIdx.x;
    float a = 0.f;
    #pragma unroll
    for (int i = 0; i < NBLK / 256; ++i) a += bsum[i * 256 + tid];   // fixed order
    red[tid] = a;
    __syncthreads();
    for (int off = 128; off > 0; off >>= 1) {
        if (tid < off) red[tid] += red[tid + off];
        __syncthreads();
    }
    if (tid == 0) out[0] = red[0] / (float)(N * S * C);
}

extern "C" void kernel_launch(void* const* d_in, const int* in_sizes, int n_in,
                              void* d_out, int out_size, void* d_ws, size_t ws_size,
                              hipStream_t stream) {
    const float* out4d  = (const float*)d_in[0];
    const int*   sample = (const int*)d_in[1];

    float*          P32  = (float*)d_ws;                                // N*S*CP f32
    unsigned short* XA   = (unsigned short*)(P32 + (size_t)N * S * CP); // N*S*XP u16
    unsigned short* XB   = XA + (size_t)N * S * XP;                     // N*S*XP u16
    unsigned*       keys = (unsigned*)(XB + (size_t)N * S * XP);        // N*NCHUNK*S u32
    float*          bsum = (float*)(keys + (size_t)N * NCHUNK * S);     // NBLK f32
    float*          outp = (float*)d_out;

    gather_k<<<(N * S * 32) / 256, 256, 0, stream>>>(out4d, sample, P32, XA, XB);
    argmax_k<<<N * 32 * NCHUNK, 256, 0, stream>>>(XA, XB, keys);
    refine_loss_k<<<NBLK, 256, 0, stream>>>(P32, keys, bsum);
    final_k<<<1, 256, 0, stream>>>(bsum, outp);
}